// Round 12
// baseline (143.959 us; speedup 1.0000x reference)
//
#include <hip/hip_runtime.h>

// CompositeLoss: fused masked reduction over (2,3,128,128,128).
// R12: LDS-tiled via async global_load_lds (DMA -> LDS, no VGPR round-trip).
// Block = 256 threads owns tile (d:2, h:4, w:128) of one b. Stages 7 arrays
// (mask, pred c0..2, target c0..2) x 448 groups (256 self + 128 d-halo plane
// + 64 h-halo rows) = 3136 float4 = 50 KB LDS, issued as ~13 wave-wide
// 16B global_load_lds ops per wave with NO consumer before the barrier ->
// max loads-in-flight, decoupled from VGPR budget (R4's failure mode).
// All neighbor terms then read from LDS; cache-side traffic 3x -> 1.75x.
// W-neighbor via __shfl_down (R11). Per-wave partial rows (no block barrier
// after compute). Boundary: halo rows/planes clamp address; consuming groups
// have dv/hv=0 so clamped garbage is annihilated (masks are exactly 0/1).
//  0:M 1:Mx(d) 2:My(h) 3:Mz(w)  4:Smae 5:Smse 6:Sbg
//  7:Sgx 8:Sgy 9:Sgz  10:Stx 11:Sty 12:Stz
#define NACC 13
#define NPAD 16
#define NBLOCKS 4096   // 2(b) * 64(d-tiles) * 32(h-tiles)
#define NROWS 16384    // NBLOCKS * 4 waves
#define NMID 64        // 16384 / 256

__device__ __forceinline__ float4 ld4(const float* p) {
    return *reinterpret_cast<const float4*>(p);
}

__device__ __forceinline__ void gload16(const float* g, float4* l) {
    __builtin_amdgcn_global_load_lds(
        (const __attribute__((address_space(1))) void*)g,
        (__attribute__((address_space(3))) void*)l, 16, 0, 0);
}

__global__ __launch_bounds__(256) void loss_main(
    const float* __restrict__ pred, const float* __restrict__ target,
    const float* __restrict__ mask, float* __restrict__ partials)
{
    // smem[a*448 + q]: a<7 = {m, p0,p1,p2, t0,t1,t2}; q<448 group layout:
    //   q<256: self  (dl=q>>7, hl=(q>>5)&3, w4=q&31)
    //   256..383: d-halo plane dl=2 (hl=(q>>5)&3, w4)
    //   384..447: h-halo rows hl=4 (dl=(q>>5)&1, w4)
    __shared__ float4 smem[3136];

    const int tid  = threadIdx.x;
    const int lane = tid & 63;
    const int wav  = tid >> 6;

    const int bid  = blockIdx.x;
    const int h0   = (bid & 31) << 2;          // h-tile origin
    const int d0   = ((bid >> 5) & 63) << 1;   // d-tile origin
    const int b    = bid >> 11;

    // ---- staging: 49 wave-wide async ops, round-robin over 4 waves ----
#pragma unroll
    for (int j = 0; j < 13; ++j) {
        const int o = wav + (j << 2);
        if (o >= 49) break;               // wave-uniform
        const int a  = o / 7;             // array
        const int oi = o - a * 7;         // 64-group chunk within array
        const int q  = (oi << 6) + lane;
        const int w4 = q & 31;
        int dl, hl;
        if (oi < 4)      { dl = q >> 7;        hl = (q >> 5) & 3; }
        else if (oi < 6) { dl = 2;             hl = (q >> 5) & 3; }
        else             { dl = (q >> 5) & 1;  hl = 4; }
        int d = d0 + dl; d = (d > 127) ? 127 : d;   // clamp (consumers have
        int h = h0 + hl; h = (h > 127) ? 127 : h;   //  dv/hv=0 at the edge)
        const int sp = d * 16384 + h * 128 + (w4 << 2);
        const float* gp;
        if (a == 0)     gp = mask   + b * 2097152 + sp;
        else if (a < 4) gp = pred   + (3 * b + a - 1) * 2097152 + sp;
        else            gp = target + (3 * b + a - 4) * 2097152 + sp;
        gload16(gp, &smem[(o << 6) + lane]);
    }
    __syncthreads();   // drains vmcnt: staging complete

    // ---- compute from LDS ----
    const int w4 = tid & 31;
    const int hl = (tid >> 5) & 3;
    const int dl = tid >> 7;
    const int d  = d0 + dl, h = h0 + hl;
    const float wv = (w4 < 31) ? 1.f : 0.f;
    const float hv = (h < 127) ? 1.f : 0.f;
    const float dv = (d < 127) ? 1.f : 0.f;

    const int qs = tid;
    const int qh = (hl < 3)  ? (tid + 32)  : (384 + (dl << 5) + w4);
    const int qd = (dl == 0) ? (tid + 128) : (256 + (hl << 5) + w4);

    float acc[NACC];
#pragma unroll
    for (int k = 0; k < NACC; ++k) acc[k] = 0.f;

    const float4 m0 = smem[qs];
    const float4 mh = smem[qh];
    const float4 md = smem[qd];
    const float m4w = __shfl_down(m0.x, 1, 64);   // w4=31 lanes: wv=0

    const float mz0 = fminf(m0.x, m0.y), mz1 = fminf(m0.y, m0.z),
                mz2 = fminf(m0.z, m0.w), mz3 = fminf(m0.w, m4w) * wv;
    const float my0 = fminf(m0.x, mh.x) * hv, my1 = fminf(m0.y, mh.y) * hv,
                my2 = fminf(m0.z, mh.z) * hv, my3 = fminf(m0.w, mh.w) * hv;
    const float mx0 = fminf(m0.x, md.x) * dv, mx1 = fminf(m0.y, md.y) * dv,
                mx2 = fminf(m0.z, md.z) * dv, mx3 = fminf(m0.w, md.w) * dv;

    acc[0] = m0.x + m0.y + m0.z + m0.w;
    acc[1] = mx0 + mx1 + mx2 + mx3;
    acc[2] = my0 + my1 + my2 + my3;
    acc[3] = mz0 + mz1 + mz2 + mz3;

#pragma unroll
    for (int c = 0; c < 3; ++c) {
        const float4 p0 = smem[(1 + c) * 448 + qs];
        const float4 t0 = smem[(4 + c) * 448 + qs];
        const float4 ph = smem[(1 + c) * 448 + qh];
        const float4 th = smem[(4 + c) * 448 + qh];
        const float4 pd = smem[(1 + c) * 448 + qd];
        const float4 td = smem[(4 + c) * 448 + qd];
        const float  p4 = __shfl_down(p0.x, 1, 64);
        const float  t4 = __shfl_down(t0.x, 1, 64);

        const float e0x = p0.x - t0.x, e0y = p0.y - t0.y,
                    e0z = p0.z - t0.z, e0w = p0.w - t0.w;
        const float e4  = p4 - t4;

        acc[4] += fabsf(e0x)*m0.x + fabsf(e0y)*m0.y
                + fabsf(e0z)*m0.z + fabsf(e0w)*m0.w;
        acc[5] += e0x*e0x*m0.x + e0y*e0y*m0.y
                + e0z*e0z*m0.z + e0w*e0w*m0.w;
        acc[6] += fabsf(p0.x)*(1.f-m0.x) + fabsf(p0.y)*(1.f-m0.y)
                + fabsf(p0.z)*(1.f-m0.z) + fabsf(p0.w)*(1.f-m0.w);

        // W direction (reference dz)
        acc[9]  += fabsf(e0y-e0x)*mz0 + fabsf(e0z-e0y)*mz1
                 + fabsf(e0w-e0z)*mz2 + fabsf(e4 -e0w)*mz3;
        acc[12] += fabsf(p0.y-p0.x)*mz0 + fabsf(p0.z-p0.y)*mz1
                 + fabsf(p0.w-p0.z)*mz2 + fabsf(p4  -p0.w)*mz3;

        // H direction (reference dy)
        acc[8]  += fabsf((ph.x-th.x)-e0x)*my0 + fabsf((ph.y-th.y)-e0y)*my1
                 + fabsf((ph.z-th.z)-e0z)*my2 + fabsf((ph.w-th.w)-e0w)*my3;
        acc[11] += fabsf(ph.x-p0.x)*my0 + fabsf(ph.y-p0.y)*my1
                 + fabsf(ph.z-p0.z)*my2 + fabsf(ph.w-p0.w)*my3;

        // D direction (reference dx)
        acc[7]  += fabsf((pd.x-td.x)-e0x)*mx0 + fabsf((pd.y-td.y)-e0y)*mx1
                 + fabsf((pd.z-td.z)-e0z)*mx2 + fabsf((pd.w-td.w)-e0w)*mx3;
        acc[10] += fabsf(pd.x-p0.x)*mx0 + fabsf(pd.y-p0.y)*mx1
                 + fabsf(pd.z-p0.z)*mx2 + fabsf(pd.w-p0.w)*mx3;
    }

    // per-wave shuffle reduce -> own partials row; no trailing barrier
    float mine = 0.f;
#pragma unroll
    for (int k = 0; k < NACC; ++k) {
        float v = acc[k];
        for (int o = 32; o > 0; o >>= 1) v += __shfl_down(v, o, 64);
        const float tot = __shfl(v, 0, 64);
        if (lane == k) mine = tot;
    }
    if (lane < NPAD)
        partials[(bid * 4 + wav) * NPAD + lane] = mine;
}

// Level 1: 64 blocks x 256 threads; thread r reads row r (4 independent
// float4), block-reduces 256 rows -> 1 row.
__global__ __launch_bounds__(256) void loss_mid(
    const float* __restrict__ partials, float* __restrict__ mid)
{
    const int r = blockIdx.x * 256 + threadIdx.x;   // exactly covers 16384
    const float* row = partials + r * NPAD;
    const float4 r0 = ld4(row);     const float4 r1 = ld4(row + 4);
    const float4 r2 = ld4(row + 8); const float4 r3 = ld4(row + 12);
    float acc[NPAD] = {r0.x, r0.y, r0.z, r0.w, r1.x, r1.y, r1.z, r1.w,
                       r2.x, r2.y, r2.z, r2.w, r3.x, r3.y, r3.z, r3.w};

    const int lane = threadIdx.x & 63;
    const int wave = threadIdx.x >> 6;
    __shared__ float red[4][NPAD];
#pragma unroll
    for (int k = 0; k < NPAD; ++k) {
        float v = acc[k];
        for (int o = 32; o > 0; o >>= 1) v += __shfl_down(v, o, 64);
        if (lane == 0) red[wave][k] = v;
    }
    __syncthreads();
    if (threadIdx.x < NPAD) {
        const int k = threadIdx.x;
        mid[blockIdx.x * NPAD + k] =
            red[0][k] + red[1][k] + red[2][k] + red[3][k];
    }
}

// Level 2: one wave; lane l reads mid row l (64 rows), shuffle-reduce,
// lane 0 does the scalar epilogue.
__global__ __launch_bounds__(64) void loss_final(
    const float* __restrict__ mid, float* __restrict__ out)
{
    const int lane = threadIdx.x;
    float acc[NPAD];
    {
        const float* row = mid + lane * NPAD;   // lane < 64 == NMID
        const float4 r0 = ld4(row);     const float4 r1 = ld4(row + 4);
        const float4 r2 = ld4(row + 8); const float4 r3 = ld4(row + 12);
        acc[0] = r0.x;  acc[1] = r0.y;  acc[2] = r0.z;  acc[3] = r0.w;
        acc[4] = r1.x;  acc[5] = r1.y;  acc[6] = r1.z;  acc[7] = r1.w;
        acc[8] = r2.x;  acc[9] = r2.y;  acc[10] = r2.z; acc[11] = r2.w;
        acc[12] = r3.x; acc[13] = r3.y; acc[14] = r3.z; acc[15] = r3.w;
    }
#pragma unroll
    for (int k = 0; k < NACC; ++k) {
        for (int o = 32; o > 0; o >>= 1) acc[k] += __shfl_down(acc[k], o, 64);
    }
    if (lane == 0) {
        const float EPS = 1e-8f;
        const float M = acc[0], Mx = acc[1], My = acc[2], Mz = acc[3];
        float loss = (acc[4] + acc[5]) / (3.f * M + EPS);   // W_MAE=1, W_MSE=1
        loss += 0.1f   * (acc[7] / (3.f*Mx + EPS) + acc[8] / (3.f*My + EPS)
                        + acc[9] / (3.f*Mz + EPS));
        loss += 0.002f * (acc[10] / (3.f*Mx + EPS) + acc[11] / (3.f*My + EPS)
                        + acc[12] / (3.f*Mz + EPS));
        const float inv = 4194304.f - M;  // B*D*H*W - M
        loss += 0.15f * acc[6] / (3.f * inv + EPS);
        out[0] = loss;
    }
}

extern "C" void kernel_launch(void* const* d_in, const int* in_sizes, int n_in,
                              void* d_out, int out_size, void* d_ws, size_t ws_size,
                              hipStream_t stream) {
    const float* pred   = (const float*)d_in[0];
    const float* target = (const float*)d_in[1];
    const float* mask   = (const float*)d_in[2];
    float* out      = (float*)d_out;
    float* partials = (float*)d_ws;                 // 16384*16 floats = 1 MiB
    float* mid      = partials + NROWS * NPAD;      // 64*16 floats

    loss_main<<<NBLOCKS, 256, 0, stream>>>(pred, target, mask, partials);
    loss_mid<<<NMID, 256, 0, stream>>>(partials, mid);
    loss_final<<<1, 64, 0, stream>>>(mid, out);
}